// Round 19
// baseline (154.671 us; speedup 1.0000x reference)
//
#include <hip/hip_runtime.h>
#include <hip/hip_fp16.h>

// CompressibleFluidLoss: out[i] = mean_x + mean_y + (p[i]-p_prev[i])/dt,
// vp = v*p per node; means are masked scatter-means over edges at src.
//
// Round 19 = r18 + micro-pass: SoA records (m u32 stream + a2 float2
// stream; 2 aligned loads/record instead of 3 unaligned dwords) and
// vectorized node_pre. Pre-committed: <4% gain -> structure is at its
// fabric floor (bucket_reduce 3.2 of 3.6 TB/s random-mix ceiling,
// chunk_sort at ~5.4 TB/s streaming ceiling).

#define NPB      2048   // nodes per bucket
#define NPB_LOG  11
#define NBUCK_MAX 512
#define CE       4096   // edges per chunk
#define CB       1024   // chunk_sort block threads
#define EPT      4      // edges per thread
#define CCAP     3456   // record cap per chunk (mean 3072, +13.9 sigma)
#define MAXCHUNK 2048
#define NHINT    4096
#define SPILLCAP (1 << 18)
#define K_OFF    1073741824.0   // 2^30

typedef unsigned long long ull;

// ---------------- fast path ----------------

__global__ void node_pre_fast(const float4* __restrict__ v2,  // 2 nodes/elt
                              const float2* __restrict__ p2,
                              uint2* __restrict__ vph2,       // 2 half2/elt
                              int* __restrict__ spill_cnt, int N2) {
    int i = blockIdx.x * blockDim.x + threadIdx.x;
    int stride = gridDim.x * blockDim.x;
    for (; i < N2; i += stride) {
        float4 vv = v2[i];
        float2 pp = p2[i];
        __half2 h0 = __float22half2_rn(make_float2(vv.x * pp.x, vv.y * pp.x));
        __half2 h1 = __float22half2_rn(make_float2(vv.z * pp.y, vv.w * pp.y));
        vph2[i] = make_uint2(*(unsigned*)&h0, *(unsigned*)&h1);
    }
    if (blockIdx.x == 0 && threadIdx.x == 0) *spill_cnt = 0;
}

__global__ __launch_bounds__(CB) void chunk_sort(
        const float2* __restrict__ ea,
        const int* __restrict__ src_idx,
        const int* __restrict__ dst_idx,
        unsigned* __restrict__ recs_m,
        float2* __restrict__ recs_a,
        unsigned short* __restrict__ off_mat,
        unsigned short* __restrict__ cnt_mat,
        uint4* __restrict__ spill,
        int* __restrict__ spill_cnt,
        int nbuck, int E) {
    __shared__ unsigned stage_m[CCAP];   // 13.8 KB
    __shared__ float2 stage_a[CCAP];     // 27.6 KB
    __shared__ int hist[NBUCK_MAX];      // 2 KB
    __shared__ int tl[NBUCK_MAX];        // 2 KB
    __shared__ int cur[NBUCK_MAX];       // 2 KB
    int c = blockIdx.x, t = threadIdx.x;
    int e0 = c * CE;

    unsigned M[EPT];
    float AX[EPT], AY[EPT];
    int K[EPT], NR[EPT];
#pragma unroll
    for (int i = 0; i < EPT; ++i) {
        int e = e0 + i * CB + t;         // coalesced per sub-iteration
        NR[i] = 0; K[i] = 0;
        if (e < E) {
            float2 a = ea[e];
            if (a.x != 0.f || a.y != 0.f) {
                int s = src_idx[e];
                int d = dst_idx[e];
                K[i] = s >> NPB_LOG;
                M[i] = (unsigned)(s & (NPB - 1)) | ((unsigned)d << NPB_LOG);
                AX[i] = a.x;
                AY[i] = a.y;
                NR[i] = 1;
            }
        }
    }
    if (t < nbuck) hist[t] = 0;
    __syncthreads();
#pragma unroll
    for (int i = 0; i < EPT; ++i)
        if (NR[i]) atomicAdd(&hist[K[i]], 1);
    __syncthreads();
    // inclusive scan hist -> tl over nbuck (<= 512)
    if (t < nbuck) tl[t] = hist[t];
    __syncthreads();
    for (int off = 1; off < NBUCK_MAX; off <<= 1) {
        int x = 0;
        if (t < nbuck && t >= off) x = tl[t - off];
        __syncthreads();
        if (t < nbuck) tl[t] += x;
        __syncthreads();
    }
    int total = tl[nbuck - 1];
    if (t < nbuck) {
        int excl = tl[t] - hist[t];
        cur[t] = excl;
        off_mat[(size_t)c * nbuck + t] = (unsigned short)excl;
        cnt_mat[(size_t)c * nbuck + t] = (unsigned short)hist[t];
    }
    __syncthreads();
    size_t rb = (size_t)c * CCAP;
    if (total <= CCAP) {
        // stage grouped by bucket, then flush linearly (coalesced, SoA)
#pragma unroll
        for (int i = 0; i < EPT; ++i)
            if (NR[i]) {
                int slot = atomicAdd(&cur[K[i]], 1);
                stage_m[slot] = M[i];
                stage_a[slot] = make_float2(AX[i], AY[i]);
            }
        __syncthreads();
        for (int j = t; j < total; j += CB) recs_m[rb + j] = stage_m[j];
        for (int j = t; j < total; j += CB) recs_a[rb + j] = stage_a[j];
    } else {
        // overflow regime (never in practice): spill list
#pragma unroll
        for (int i = 0; i < EPT; ++i)
            if (NR[i]) {
                int slot = atomicAdd(&cur[K[i]], 1);
                if (slot < CCAP) {
                    recs_m[rb + slot] = M[i];
                    recs_a[rb + slot] = make_float2(AX[i], AY[i]);
                } else {
                    int sp = atomicAdd(spill_cnt, 1);
                    if (sp < SPILLCAP)
                        spill[sp] = make_uint4(M[i], __float_as_uint(AX[i]),
                                               __float_as_uint(AY[i]), (unsigned)K[i]);
                }
            }
    }
}

__global__ __launch_bounds__(1024) void bucket_reduce(
        const unsigned* __restrict__ recs_m,
        const float2* __restrict__ recs_a,
        const unsigned short* __restrict__ off_mat,
        const unsigned short* __restrict__ cnt_mat,
        const float2* __restrict__ v,
        const float* __restrict__ p,
        const __half2* __restrict__ vph,
        const uint4* __restrict__ spill,
        const int* __restrict__ spill_cnt,
        const float* __restrict__ p_prev,
        const float* __restrict__ dt_ptr,
        float* __restrict__ out,
        int nchunk, int nbuck, int N) {
    __shared__ float2 vps[NPB];            // 16 KB (f32 source side, from v*p)
    __shared__ double2 acc[NPB];           // 32 KB packed (sum + cnt*2^30)
    __shared__ int glen[MAXCHUNK];         // 8 KB -> inclusive prefix
    __shared__ int goff[MAXCHUNK];         // 8 KB
    __shared__ unsigned short hint[NHINT]; // 8 KB: record 8j -> chunk
    __shared__ int s_sp;
    int k = blockIdx.x, t = threadIdx.x;
    int g0 = k * NPB;
    for (int i = t; i < NPB; i += 1024) {
        int g = g0 + i;
        float2 vi = (g < N) ? v[g] : make_float2(0.f, 0.f);
        float pi = (g < N) ? p[g] : 0.f;
        vps[i] = make_float2(vi.x * pi, vi.y * pi);
        acc[i] = make_double2(0.0, 0.0);
    }
    if (t == 0) s_sp = *spill_cnt;
    for (int c = t; c < MAXCHUNK; c += 1024) {
        int len = 0, off = 0;
        if (c < nchunk) {
            off = off_mat[(size_t)c * nbuck + k];
            int cnt = cnt_mat[(size_t)c * nbuck + k];
            len = min(cnt, max(0, CCAP - off));   // clamp overflow'd tail
        }
        goff[c] = off;
        glen[c] = len;
    }
    __syncthreads();
    // inclusive scan glen over MAXCHUNK (2048) with 1024 threads
    for (int off = 1; off < MAXCHUNK; off <<= 1) {
        int i0 = t, i1 = t + 1024;
        int x0 = (i0 >= off) ? glen[i0 - off] : 0;
        int x1 = glen[i1 - off];
        __syncthreads();
        glen[i0] += x0;
        glen[i1] += x1;
        __syncthreads();
    }
    int total = glen[MAXCHUNK - 1];
    // build hint table: hint[j] = first chunk with glen[chunk] > 8j
    int nh = min((total + 7) >> 3, NHINT);
    for (int j = t; j < nh; j += 1024) {
        int target = j << 3;
        int lo = 0, hi = nchunk - 1;
        while (lo < hi) {
            int mid = (lo + hi) >> 1;
            if (glen[mid] > target) hi = mid; else lo = mid + 1;
        }
        hint[j] = (unsigned short)lo;
    }
    __syncthreads();
    // interleaved (coalesced) record walk with O(1) chunk lookup
    for (int idx = t; idx < total; idx += 1024) {
        int cur = hint[idx >> 3];
        while (glen[cur] <= idx) ++cur;      // <= ~2 steps
        int pre = cur ? glen[cur - 1] : 0;
        size_t ri = (size_t)cur * CCAP + goff[cur] + (idx - pre);
        unsigned m = recs_m[ri];
        float2 a2 = recs_a[ri];
        int sl = (int)(m & (NPB - 1u));
        int d = (int)(m >> NPB_LOG);
        float2 vpd = __half22float2(vph[d]);   // ONE gather per edge
        float2 vs = vps[sl];
        if (a2.x != 0.f)
            unsafeAtomicAdd(&acc[sl].x, (double)((vpd.x - vs.x) / a2.x) + K_OFF);
        if (a2.y != 0.f)
            unsafeAtomicAdd(&acc[sl].y, (double)((vpd.y - vs.y) / a2.y) + K_OFF);
    }
    __syncthreads();
    // spill list (nonempty only in the never-hit overflow regime)
    int nsp = min(s_sp, SPILLCAP);
    for (int i = t; i < nsp; i += 1024) {
        uint4 r = spill[i];
        if ((int)r.w != k) continue;
        int sl = (int)(r.x & (NPB - 1u));
        int d = (int)(r.x >> NPB_LOG);
        float ax = __uint_as_float(r.y);
        float ay = __uint_as_float(r.z);
        float2 vpd = __half22float2(vph[d]);
        float2 vs = vps[sl];
        if (ax != 0.f)
            unsafeAtomicAdd(&acc[sl].x, (double)((vpd.x - vs.x) / ax) + K_OFF);
        if (ay != 0.f)
            unsafeAtomicAdd(&acc[sl].y, (double)((vpd.y - vs.y) / ay) + K_OFF);
    }
    if (nsp) __syncthreads();
    float inv_dt = 1.0f / dt_ptr[0];
    for (int i = t; i < NPB; i += 1024) {
        int g = g0 + i;
        if (g < N) {
            double2 A = acc[i];
            double cx = rint(A.x * (1.0 / K_OFF));
            double sx = A.x - cx * K_OFF;
            double cy = rint(A.y * (1.0 / K_OFF));
            double sy = A.y - cy * K_OFF;
            out[g] = (float)(sx / fmax(cx, 1.0)) + (float)(sy / fmax(cy, 1.0))
                   + (p[g] - p_prev[g]) * inv_dt;
        }
    }
}

// ---------------- fallback path (round-5: f64-packed atomics, 390us) -------

__global__ void fb_node_pre(const float2* __restrict__ v,
                            const float* __restrict__ p,
                            float2* __restrict__ vp,
                            double2* __restrict__ acc, int N) {
    int i = blockIdx.x * blockDim.x + threadIdx.x;
    int stride = gridDim.x * blockDim.x;
    for (; i < N; i += stride) {
        float2 vi = v[i];
        float pi = p[i];
        vp[i] = make_float2(vi.x * pi, vi.y * pi);
        acc[i] = make_double2(0.0, 0.0);
    }
}

__global__ void fb_edge_scatter(const float2* __restrict__ vp,
                                const float2* __restrict__ ea,
                                const int* __restrict__ src_idx,
                                const int* __restrict__ dst_idx,
                                double2* __restrict__ acc, int E) {
    int e = blockIdx.x * blockDim.x + threadIdx.x;
    if (e >= E) return;
    float2 a = ea[e];
    bool mx = (a.x != 0.f);
    bool my = (a.y != 0.f);
    if (!mx && !my) return;
    int s = src_idx[e];
    int d = dst_idx[e];
    float2 vs = vp[s];
    float2 vd = vp[d];
    double* basep = (double*)&acc[s];
    if (mx) unsafeAtomicAdd(basep + 0, (double)((vd.x - vs.x) / a.x) + K_OFF);
    if (my) unsafeAtomicAdd(basep + 1, (double)((vd.y - vs.y) / a.y) + K_OFF);
}

__global__ void fb_node_final(const double2* __restrict__ acc,
                              const float* __restrict__ p,
                              const float* __restrict__ p_prev,
                              const float* __restrict__ dt_ptr,
                              float* __restrict__ out, int N) {
    int i = blockIdx.x * blockDim.x + threadIdx.x;
    int stride = gridDim.x * blockDim.x;
    float inv_dt = 1.0f / dt_ptr[0];
    for (; i < N; i += stride) {
        double2 A = acc[i];
        double cx = rint(A.x * (1.0 / K_OFF));
        double sx = A.x - cx * K_OFF;
        double cy = rint(A.y * (1.0 / K_OFF));
        double sy = A.y - cy * K_OFF;
        out[i] = (float)(sx / fmax(cx, 1.0)) + (float)(sy / fmax(cy, 1.0))
               + (p[i] - p_prev[i]) * inv_dt;
    }
}

// ---------------- launch ----------------

extern "C" void kernel_launch(void* const* d_in, const int* in_sizes, int n_in,
                              void* d_out, int out_size, void* d_ws, size_t ws_size,
                              hipStream_t stream) {
    const float2* v_x    = (const float2*)d_in[0];
    const float*  p_x    = (const float*)d_in[2];
    const float*  p_prev = (const float*)d_in[3];
    const float*  dt     = (const float*)d_in[9];
    const float2* ea     = (const float2*)d_in[10];
    const int*    eidx   = (const int*)d_in[11];

    const int N = in_sizes[2];
    const int E = in_sizes[10] / 2;
    const int* src_idx = eidx;
    const int* dst_idx = eidx + E;

    const int nbuck  = (N + NPB - 1) >> NPB_LOG;
    const int nchunk = (E + CE - 1) / CE;

    // ws: vph 4 | flag | off 2 | cnt 2 | spill 4 | recs_m 28.3 | recs_a 56.6 MB
    char* w = (char*)d_ws;
    __half2* vph      = (__half2*)w;  w += (size_t)N * sizeof(__half2);
    int*     spill_cnt= (int*)w;      w += 16;
    unsigned short* off_mat = (unsigned short*)w;  w += (size_t)nchunk * nbuck * sizeof(unsigned short);
    unsigned short* cnt_mat = (unsigned short*)w;  w += (size_t)nchunk * nbuck * sizeof(unsigned short);
    w = (char*)(((uintptr_t)w + 15) & ~(uintptr_t)15);
    uint4*   spill    = (uint4*)w;    w += (size_t)SPILLCAP * sizeof(uint4);
    unsigned* recs_m  = (unsigned*)w; w += (size_t)nchunk * CCAP * sizeof(unsigned);
    w = (char*)(((uintptr_t)w + 15) & ~(uintptr_t)15);
    float2*  recs_a   = (float2*)w;   w += (size_t)nchunk * CCAP * sizeof(float2);
    size_t need_fast = (size_t)(w - (char*)d_ws);

    if (nbuck <= NBUCK_MAX && nchunk <= MAXCHUNK && N <= (1 << 20)
        && (N % 2) == 0 && ws_size >= need_fast) {
        node_pre_fast<<<2048, 256, 0, stream>>>((const float4*)v_x,
                                                (const float2*)p_x,
                                                (uint2*)vph, spill_cnt, N / 2);
        chunk_sort<<<nchunk, CB, 0, stream>>>(ea, src_idx, dst_idx,
                                              recs_m, recs_a, off_mat, cnt_mat,
                                              spill, spill_cnt, nbuck, E);
        bucket_reduce<<<nbuck, 1024, 0, stream>>>(recs_m, recs_a, off_mat, cnt_mat,
                                                  v_x, p_x, vph,
                                                  spill, spill_cnt,
                                                  p_prev, dt,
                                                  (float*)d_out, nchunk, nbuck, N);
    } else {
        float2*  fvp  = (float2*)d_ws;
        double2* facc = (double2*)((char*)d_ws + (size_t)N * sizeof(float2));
        fb_node_pre<<<2048, 256, 0, stream>>>(v_x, p_x, fvp, facc, N);
        fb_edge_scatter<<<(E + 255) / 256, 256, 0, stream>>>(
            fvp, ea, src_idx, dst_idx, facc, E);
        fb_node_final<<<2048, 256, 0, stream>>>(
            facc, p_x, p_prev, dt, (float*)d_out, N);
    }
}

// Round 20
// 130.965 us; speedup vs baseline: 1.1810x; 1.1810x over previous
//
#include <hip/hip_runtime.h>
#include <hip/hip_fp16.h>

// CompressibleFluidLoss: out[i] = mean_x + mean_y + (p[i]-p_prev[i])/dt,
// vp = v*p per node; means are masked scatter-means over edges at src.
//
// FINAL (r18 revert): merged per-EDGE 12B AoS records (meta = s_local|d<<11,
// ax, ay; masks implicit in ax/ay != 0). One random fp16x2 gather per edge.
// Pipeline: node_pre (vp -> half2) -> chunk_sort (per-4096-edge-block LDS
// counting sort, coalesced flush to per-chunk region + off/cnt ushort
// matrices) -> bucket_reduce (per-2048-node-bucket: LDS-staged vps, hint-
// table chunk locator, packed-f64 LDS accumulation sum+cnt*2^30, fused
// epilogue). r19's SoA split regressed (2 line-touches/record); r13/r15/r19
// all confirm: line-touch count is the binding resource. bucket_reduce runs
// at ~89% of the 3.6 TB/s random-mix fabric ceiling; chunk_sort at the
// streaming ceiling -> structural floor ~131us.

#define NPB      2048   // nodes per bucket
#define NPB_LOG  11
#define NBUCK_MAX 512
#define CE       4096   // edges per chunk
#define CB       1024   // chunk_sort block threads
#define EPT      4      // edges per thread
#define CCAP     3456   // record cap per chunk (mean 3072, +13.9 sigma)
#define MAXCHUNK 2048
#define NHINT    4096
#define SPILLCAP (1 << 18)
#define K_OFF    1073741824.0   // 2^30

typedef unsigned long long ull;

struct __align__(4) Rec12 { unsigned m; float ax, ay; };   // 12 bytes

// ---------------- fast path ----------------

__global__ void node_pre_fast(const float2* __restrict__ v,
                              const float* __restrict__ p,
                              __half2* __restrict__ vph,
                              int* __restrict__ spill_cnt, int N) {
    int i = blockIdx.x * blockDim.x + threadIdx.x;
    int stride = gridDim.x * blockDim.x;
    for (; i < N; i += stride) {
        float2 vi = v[i];
        float pi = p[i];
        vph[i] = __float22half2_rn(make_float2(vi.x * pi, vi.y * pi));
    }
    if (blockIdx.x == 0 && threadIdx.x == 0) *spill_cnt = 0;
}

__global__ __launch_bounds__(CB) void chunk_sort(
        const float2* __restrict__ ea,
        const int* __restrict__ src_idx,
        const int* __restrict__ dst_idx,
        Rec12* __restrict__ recs,
        unsigned short* __restrict__ off_mat,
        unsigned short* __restrict__ cnt_mat,
        uint4* __restrict__ spill,
        int* __restrict__ spill_cnt,
        int nbuck, int E) {
    __shared__ Rec12 stage[CCAP];        // 41.5 KB
    __shared__ int hist[NBUCK_MAX];      // 2 KB
    __shared__ int tl[NBUCK_MAX];        // 2 KB
    __shared__ int cur[NBUCK_MAX];       // 2 KB
    int c = blockIdx.x, t = threadIdx.x;
    int e0 = c * CE;

    unsigned M[EPT];
    float AX[EPT], AY[EPT];
    int K[EPT], NR[EPT];
#pragma unroll
    for (int i = 0; i < EPT; ++i) {
        int e = e0 + i * CB + t;         // coalesced per sub-iteration
        NR[i] = 0; K[i] = 0;
        if (e < E) {
            float2 a = ea[e];
            if (a.x != 0.f || a.y != 0.f) {
                int s = src_idx[e];
                int d = dst_idx[e];
                K[i] = s >> NPB_LOG;
                M[i] = (unsigned)(s & (NPB - 1)) | ((unsigned)d << NPB_LOG);
                AX[i] = a.x;
                AY[i] = a.y;
                NR[i] = 1;
            }
        }
    }
    if (t < nbuck) hist[t] = 0;
    __syncthreads();
#pragma unroll
    for (int i = 0; i < EPT; ++i)
        if (NR[i]) atomicAdd(&hist[K[i]], 1);
    __syncthreads();
    // inclusive scan hist -> tl over nbuck (<= 512)
    if (t < nbuck) tl[t] = hist[t];
    __syncthreads();
    for (int off = 1; off < NBUCK_MAX; off <<= 1) {
        int x = 0;
        if (t < nbuck && t >= off) x = tl[t - off];
        __syncthreads();
        if (t < nbuck) tl[t] += x;
        __syncthreads();
    }
    int total = tl[nbuck - 1];
    if (t < nbuck) {
        int excl = tl[t] - hist[t];
        cur[t] = excl;
        off_mat[(size_t)c * nbuck + t] = (unsigned short)excl;
        cnt_mat[(size_t)c * nbuck + t] = (unsigned short)hist[t];
    }
    __syncthreads();
    size_t rb = (size_t)c * CCAP;
    if (total <= CCAP) {
        // stage grouped by bucket, then flush linearly (coalesced)
#pragma unroll
        for (int i = 0; i < EPT; ++i)
            if (NR[i]) {
                int slot = atomicAdd(&cur[K[i]], 1);
                stage[slot].m = M[i];
                stage[slot].ax = AX[i];
                stage[slot].ay = AY[i];
            }
        __syncthreads();
        for (int j = t; j < total; j += CB) recs[rb + j] = stage[j];
    } else {
        // overflow regime (never in practice): spill list
#pragma unroll
        for (int i = 0; i < EPT; ++i)
            if (NR[i]) {
                int slot = atomicAdd(&cur[K[i]], 1);
                if (slot < CCAP) {
                    recs[rb + slot].m = M[i];
                    recs[rb + slot].ax = AX[i];
                    recs[rb + slot].ay = AY[i];
                } else {
                    int sp = atomicAdd(spill_cnt, 1);
                    if (sp < SPILLCAP)
                        spill[sp] = make_uint4(M[i], __float_as_uint(AX[i]),
                                               __float_as_uint(AY[i]), (unsigned)K[i]);
                }
            }
    }
}

__global__ __launch_bounds__(1024) void bucket_reduce(
        const Rec12* __restrict__ recs,
        const unsigned short* __restrict__ off_mat,
        const unsigned short* __restrict__ cnt_mat,
        const float2* __restrict__ v,
        const float* __restrict__ p,
        const __half2* __restrict__ vph,
        const uint4* __restrict__ spill,
        const int* __restrict__ spill_cnt,
        const float* __restrict__ p_prev,
        const float* __restrict__ dt_ptr,
        float* __restrict__ out,
        int nchunk, int nbuck, int N) {
    __shared__ float2 vps[NPB];            // 16 KB (f32 source side, from v*p)
    __shared__ double2 acc[NPB];           // 32 KB packed (sum + cnt*2^30)
    __shared__ int glen[MAXCHUNK];         // 8 KB -> inclusive prefix
    __shared__ int goff[MAXCHUNK];         // 8 KB
    __shared__ unsigned short hint[NHINT]; // 8 KB: record 8j -> chunk
    __shared__ int s_sp;
    int k = blockIdx.x, t = threadIdx.x;
    int g0 = k * NPB;
    for (int i = t; i < NPB; i += 1024) {
        int g = g0 + i;
        float2 vi = (g < N) ? v[g] : make_float2(0.f, 0.f);
        float pi = (g < N) ? p[g] : 0.f;
        vps[i] = make_float2(vi.x * pi, vi.y * pi);
        acc[i] = make_double2(0.0, 0.0);
    }
    if (t == 0) s_sp = *spill_cnt;
    for (int c = t; c < MAXCHUNK; c += 1024) {
        int len = 0, off = 0;
        if (c < nchunk) {
            off = off_mat[(size_t)c * nbuck + k];
            int cnt = cnt_mat[(size_t)c * nbuck + k];
            len = min(cnt, max(0, CCAP - off));   // clamp overflow'd tail
        }
        goff[c] = off;
        glen[c] = len;
    }
    __syncthreads();
    // inclusive scan glen over MAXCHUNK (2048) with 1024 threads
    for (int off = 1; off < MAXCHUNK; off <<= 1) {
        int i0 = t, i1 = t + 1024;
        int x0 = (i0 >= off) ? glen[i0 - off] : 0;
        int x1 = glen[i1 - off];
        __syncthreads();
        glen[i0] += x0;
        glen[i1] += x1;
        __syncthreads();
    }
    int total = glen[MAXCHUNK - 1];
    // build hint table: hint[j] = first chunk with glen[chunk] > 8j
    int nh = min((total + 7) >> 3, NHINT);
    for (int j = t; j < nh; j += 1024) {
        int target = j << 3;
        int lo = 0, hi = nchunk - 1;
        while (lo < hi) {
            int mid = (lo + hi) >> 1;
            if (glen[mid] > target) hi = mid; else lo = mid + 1;
        }
        hint[j] = (unsigned short)lo;
    }
    __syncthreads();
    // interleaved (coalesced) record walk with O(1) chunk lookup
    for (int idx = t; idx < total; idx += 1024) {
        int cur = hint[idx >> 3];
        while (glen[cur] <= idx) ++cur;      // <= ~2 steps
        int pre = cur ? glen[cur - 1] : 0;
        Rec12 r = recs[(size_t)cur * CCAP + goff[cur] + (idx - pre)];
        int sl = (int)(r.m & (NPB - 1u));
        int d = (int)(r.m >> NPB_LOG);
        float2 vpd = __half22float2(vph[d]);   // ONE gather per edge
        float2 vs = vps[sl];
        if (r.ax != 0.f)
            unsafeAtomicAdd(&acc[sl].x, (double)((vpd.x - vs.x) / r.ax) + K_OFF);
        if (r.ay != 0.f)
            unsafeAtomicAdd(&acc[sl].y, (double)((vpd.y - vs.y) / r.ay) + K_OFF);
    }
    __syncthreads();
    // spill list (nonempty only in the never-hit overflow regime)
    int nsp = min(s_sp, SPILLCAP);
    for (int i = t; i < nsp; i += 1024) {
        uint4 r = spill[i];
        if ((int)r.w != k) continue;
        int sl = (int)(r.x & (NPB - 1u));
        int d = (int)(r.x >> NPB_LOG);
        float ax = __uint_as_float(r.y);
        float ay = __uint_as_float(r.z);
        float2 vpd = __half22float2(vph[d]);
        float2 vs = vps[sl];
        if (ax != 0.f)
            unsafeAtomicAdd(&acc[sl].x, (double)((vpd.x - vs.x) / ax) + K_OFF);
        if (ay != 0.f)
            unsafeAtomicAdd(&acc[sl].y, (double)((vpd.y - vs.y) / ay) + K_OFF);
    }
    if (nsp) __syncthreads();
    float inv_dt = 1.0f / dt_ptr[0];
    for (int i = t; i < NPB; i += 1024) {
        int g = g0 + i;
        if (g < N) {
            double2 A = acc[i];
            double cx = rint(A.x * (1.0 / K_OFF));
            double sx = A.x - cx * K_OFF;
            double cy = rint(A.y * (1.0 / K_OFF));
            double sy = A.y - cy * K_OFF;
            out[g] = (float)(sx / fmax(cx, 1.0)) + (float)(sy / fmax(cy, 1.0))
                   + (p[g] - p_prev[g]) * inv_dt;
        }
    }
}

// ---------------- fallback path (round-5: f64-packed atomics, 390us) -------

__global__ void fb_node_pre(const float2* __restrict__ v,
                            const float* __restrict__ p,
                            float2* __restrict__ vp,
                            double2* __restrict__ acc, int N) {
    int i = blockIdx.x * blockDim.x + threadIdx.x;
    int stride = gridDim.x * blockDim.x;
    for (; i < N; i += stride) {
        float2 vi = v[i];
        float pi = p[i];
        vp[i] = make_float2(vi.x * pi, vi.y * pi);
        acc[i] = make_double2(0.0, 0.0);
    }
}

__global__ void fb_edge_scatter(const float2* __restrict__ vp,
                                const float2* __restrict__ ea,
                                const int* __restrict__ src_idx,
                                const int* __restrict__ dst_idx,
                                double2* __restrict__ acc, int E) {
    int e = blockIdx.x * blockDim.x + threadIdx.x;
    if (e >= E) return;
    float2 a = ea[e];
    bool mx = (a.x != 0.f);
    bool my = (a.y != 0.f);
    if (!mx && !my) return;
    int s = src_idx[e];
    int d = dst_idx[e];
    float2 vs = vp[s];
    float2 vd = vp[d];
    double* basep = (double*)&acc[s];
    if (mx) unsafeAtomicAdd(basep + 0, (double)((vd.x - vs.x) / a.x) + K_OFF);
    if (my) unsafeAtomicAdd(basep + 1, (double)((vd.y - vs.y) / a.y) + K_OFF);
}

__global__ void fb_node_final(const double2* __restrict__ acc,
                              const float* __restrict__ p,
                              const float* __restrict__ p_prev,
                              const float* __restrict__ dt_ptr,
                              float* __restrict__ out, int N) {
    int i = blockIdx.x * blockDim.x + threadIdx.x;
    int stride = gridDim.x * blockDim.x;
    float inv_dt = 1.0f / dt_ptr[0];
    for (; i < N; i += stride) {
        double2 A = acc[i];
        double cx = rint(A.x * (1.0 / K_OFF));
        double sx = A.x - cx * K_OFF;
        double cy = rint(A.y * (1.0 / K_OFF));
        double sy = A.y - cy * K_OFF;
        out[i] = (float)(sx / fmax(cx, 1.0)) + (float)(sy / fmax(cy, 1.0))
               + (p[i] - p_prev[i]) * inv_dt;
    }
}

// ---------------- launch ----------------

extern "C" void kernel_launch(void* const* d_in, const int* in_sizes, int n_in,
                              void* d_out, int out_size, void* d_ws, size_t ws_size,
                              hipStream_t stream) {
    const float2* v_x    = (const float2*)d_in[0];
    const float*  p_x    = (const float*)d_in[2];
    const float*  p_prev = (const float*)d_in[3];
    const float*  dt     = (const float*)d_in[9];
    const float2* ea     = (const float2*)d_in[10];
    const int*    eidx   = (const int*)d_in[11];

    const int N = in_sizes[2];
    const int E = in_sizes[10] / 2;
    const int* src_idx = eidx;
    const int* dst_idx = eidx + E;

    const int nbuck  = (N + NPB - 1) >> NPB_LOG;
    const int nchunk = (E + CE - 1) / CE;

    // ws: vph 4 | flag | off 2 | cnt 2 | spill 4 | recs 85 MB  (~97 MB)
    char* w = (char*)d_ws;
    __half2* vph      = (__half2*)w;  w += (size_t)N * sizeof(__half2);
    int*     spill_cnt= (int*)w;      w += 16;
    unsigned short* off_mat = (unsigned short*)w;  w += (size_t)nchunk * nbuck * sizeof(unsigned short);
    unsigned short* cnt_mat = (unsigned short*)w;  w += (size_t)nchunk * nbuck * sizeof(unsigned short);
    w = (char*)(((uintptr_t)w + 15) & ~(uintptr_t)15);
    uint4*   spill    = (uint4*)w;    w += (size_t)SPILLCAP * sizeof(uint4);
    Rec12*   recs     = (Rec12*)w;    w += (size_t)nchunk * CCAP * sizeof(Rec12);
    size_t need_fast = (size_t)(w - (char*)d_ws);

    if (nbuck <= NBUCK_MAX && nchunk <= MAXCHUNK && N <= (1 << 20)
        && ws_size >= need_fast) {
        node_pre_fast<<<2048, 256, 0, stream>>>(v_x, p_x, vph, spill_cnt, N);
        chunk_sort<<<nchunk, CB, 0, stream>>>(ea, src_idx, dst_idx,
                                              recs, off_mat, cnt_mat,
                                              spill, spill_cnt, nbuck, E);
        bucket_reduce<<<nbuck, 1024, 0, stream>>>(recs, off_mat, cnt_mat,
                                                  v_x, p_x, vph,
                                                  spill, spill_cnt,
                                                  p_prev, dt,
                                                  (float*)d_out, nchunk, nbuck, N);
    } else {
        float2*  fvp  = (float2*)d_ws;
        double2* facc = (double2*)((char*)d_ws + (size_t)N * sizeof(float2));
        fb_node_pre<<<2048, 256, 0, stream>>>(v_x, p_x, fvp, facc, N);
        fb_edge_scatter<<<(E + 255) / 256, 256, 0, stream>>>(
            fvp, ea, src_idx, dst_idx, facc, E);
        fb_node_final<<<2048, 256, 0, stream>>>(
            facc, p_x, p_prev, dt, (float*)d_out, N);
    }
}